// Round 4
// baseline (418.213 us; speedup 1.0000x reference)
//
#include <hip/hip_runtime.h>
#include <math.h>

#define N 512
#define H 12
#define CC 16      // C
#define CZ 128
#define CS 384
#define PQ 4
#define PV 8
#define CATR 2017

// ---------------------------------------------------------------------------
// Kernel 1: all projections. out[o,n] = sum_c W_sel[o][c] * s[c,n], o in [0,1152)
// ---------------------------------------------------------------------------
__global__ __launch_bounds__(256) void k_proj(
    const float* __restrict__ s,
    const float* __restrict__ Wq, const float* __restrict__ Wk, const float* __restrict__ Wv,
    const float* __restrict__ Wqp, const float* __restrict__ Wkp, const float* __restrict__ Wvp,
    float* __restrict__ proj)
{
    __shared__ float Wt[16][33];
    __shared__ float St[32][128];
    int t = threadIdx.x;
    int o0 = blockIdx.x * 16;
    int n0 = blockIdx.y * 128;
    const float* Wsrc; int orow;
    if (o0 < 192)      { Wsrc = Wq;  orow = o0; }
    else if (o0 < 384) { Wsrc = Wk;  orow = o0-192; }
    else if (o0 < 576) { Wsrc = Wv;  orow = o0-384; }
    else if (o0 < 720) { Wsrc = Wqp; orow = o0-576; }
    else if (o0 < 864) { Wsrc = Wkp; orow = o0-720; }
    else               { Wsrc = Wvp; orow = o0-864; }

    int og = t >> 6, nl = t & 63;
    float acc[4][2] = {};
    for (int c0 = 0; c0 < CS; c0 += 32) {
        __syncthreads();
        for (int k = 0; k < 2; k++) {
            int idx = t + k*256;
            int oo = idx >> 5, ccol = idx & 31;
            Wt[oo][ccol] = Wsrc[(orow+oo)*CS + c0 + ccol];
        }
        for (int k = 0; k < 4; k++) {
            int idx = t + k*256;
            int ccr = idx >> 5, nn4 = idx & 31;
            float4 v = *(const float4*)&s[(c0+ccr)*N + n0 + nn4*4];
            *(float4*)&St[ccr][nn4*4] = v;
        }
        __syncthreads();
        for (int kk = 0; kk < 32; kk++) {
            float sv0 = St[kk][nl], sv1 = St[kk][nl+64];
            #pragma unroll
            for (int r = 0; r < 4; r++) {
                float w = Wt[og*4+r][kk];
                acc[r][0] += w * sv0;
                acc[r][1] += w * sv1;
            }
        }
    }
    for (int r = 0; r < 4; r++) {
        int o = o0 + og*4 + r;
        proj[o*N + n0 + nl]      = acc[r][0];
        proj[o*N + n0 + 64 + nl] = acc[r][1];
    }
}

// ---------------------------------------------------------------------------
// Kernel 2: apply frames.
// ---------------------------------------------------------------------------
__global__ void k_frames(const float* __restrict__ proj,
                         const float* __restrict__ t_r, const float* __restrict__ t_t,
                         float* __restrict__ qg, float* __restrict__ kg, float* __restrict__ vg)
{
    int gid = blockIdx.x * blockDim.x + threadIdx.x;
    int n = gid & (N-1);
    int hp = gid >> 9;
    if (hp >= 192) return;
    const float* src; float* dst; int rowb, stride;
    if (hp < 48)      { src = proj + 576*N; dst = qg; rowb = hp;    stride = 48; }
    else if (hp < 96) { src = proj + 720*N; dst = kg; rowb = hp-48; stride = 48; }
    else              { src = proj + 864*N; dst = vg; rowb = hp-96; stride = 96; }
    float x0 = src[(rowb + 0*stride)*N + n];
    float x1 = src[(rowb + 1*stride)*N + n];
    float x2 = src[(rowb + 2*stride)*N + n];
    #pragma unroll
    for (int d = 0; d < 3; d++) {
        float r0 = t_r[(n*3+d)*3+0], r1 = t_r[(n*3+d)*3+1], r2 = t_r[(n*3+d)*3+2];
        dst[(rowb + d*stride)*N + n] = r0*x0 + r1*x1 + r2*x2 + t_t[n*3+d];
    }
}

// ---------------------------------------------------------------------------
// Kernel 2b: squared norms per (h,n).
// ---------------------------------------------------------------------------
__global__ void k_sq(const float* __restrict__ qg, const float* __restrict__ kg,
                     float* __restrict__ sq_q, float* __restrict__ sq_k)
{
    int gid = blockIdx.x * blockDim.x + threadIdx.x;
    int n = gid & (N-1);
    int sel = gid >> 9;
    int h = sel % H;
    const float* g = (sel < H) ? qg : kg;
    float* outp = (sel < H) ? sq_q : sq_k;
    float acc = 0.f;
    #pragma unroll
    for (int d = 0; d < 3; d++)
        #pragma unroll
        for (int p = 0; p < PQ; p++) {
            float v = g[(size_t)((d*H + h)*PQ + p)*N + n];
            acc += v*v;
        }
    outp[h*N + n] = acc;
}

// ---------------------------------------------------------------------------
// Kernel 3a: raw logits -> a buffer. grid (512 i, 2 jc). 4 waves, each a
// wave-uniform c-quarter (s_load weights), LDS tree reduce, wave 0 stores.
// ---------------------------------------------------------------------------
__global__ __launch_bounds__(256) void k_logits(
    const float* __restrict__ z, const float* __restrict__ proj,
    const float* __restrict__ qg, const float* __restrict__ kg,
    const float* __restrict__ sq_q, const float* __restrict__ sq_k,
    const float* __restrict__ Wb, const float* __restrict__ gamma,
    float* __restrict__ a)
{
    __shared__ float red[12*2*256];      // 24 KB
    int i = blockIdx.x;
    int jc = blockIdx.y;
    int t = threadIdx.x;
    int jl = t & 63;
    int cgu = __builtin_amdgcn_readfirstlane(t >> 6);   // wave id, uniform
    int j = jc*256 + jl*4;
    const size_t NN = (size_t)N*N;
    const float w_l  = 0.57735026918962584f;   // sqrt(1/3)
    const float w_c2 = 0.11785113019775793f;   // sqrt(1/18)/2

    float ch[12];
    #pragma unroll
    for (int h = 0; h < 12; h++) {
        float g = gamma[h];
        float sp = (g > 20.f) ? g : log1pf(expf(g));
        ch[h] = sp * w_c2;
    }

    float acc[12][4] = {};

    // ---- b_bias: 32 c per wave, 8 loads in flight
    {
        const float* zp = z + (size_t)(cgu*32)*NN + (size_t)i*N + j;
        for (int cc = 0; cc < 32; cc += 8) {
            float4 zb[8];
            #pragma unroll
            for (int u = 0; u < 8; u++)
                zb[u] = *(const float4*)(zp + (size_t)(cc+u)*NN);
            #pragma unroll
            for (int u = 0; u < 8; u++) {
                int c = cgu*32 + cc + u;
                #pragma unroll
                for (int h = 0; h < 12; h++) {
                    float w = Wb[h*CZ + c];           // uniform -> s_load
                    acc[h][0] += w*zb[u].x; acc[h][1] += w*zb[u].y;
                    acc[h][2] += w*zb[u].z; acc[h][3] += w*zb[u].w;
                }
            }
        }
    }
    // ---- qk/4: 4 c per wave
    {
        const float* q  = proj;
        const float* kk = proj + 192*N;
        #pragma unroll
        for (int cc = 0; cc < 4; cc++) {
            int c = cgu*4 + cc;
            #pragma unroll
            for (int h = 0; h < 12; h++) {
                int r = c*12 + h;
                float qv = 0.25f * q[(size_t)r*N + i];   // uniform
                float4 k4 = *(const float4*)&kk[(size_t)r*N + j];
                acc[h][0] += qv*k4.x; acc[h][1] += qv*k4.y;
                acc[h][2] += qv*k4.z; acc[h][3] += qv*k4.w;
            }
        }
    }
    // ---- +2*ch*(qg.kg): 3 dp per wave
    {
        #pragma unroll
        for (int dd = 0; dd < 3; dd++) {
            int dp = cgu*3 + dd; int d = dp >> 2, p = dp & 3;
            #pragma unroll
            for (int h = 0; h < 12; h++) {
                int r = (d*12 + h)*4 + p;
                float qv = 2.f * ch[h] * qg[(size_t)r*N + i];  // uniform row
                float4 k4 = *(const float4*)&kg[(size_t)r*N + j];
                acc[h][0] += qv*k4.x; acc[h][1] += qv*k4.y;
                acc[h][2] += qv*k4.z; acc[h][3] += qv*k4.w;
            }
        }
    }

    // ---- tree reduce across 4 waves
    if (cgu >= 2) {
        #pragma unroll
        for (int h = 0; h < 12; h++) {
            float4 v; v.x=acc[h][0]; v.y=acc[h][1]; v.z=acc[h][2]; v.w=acc[h][3];
            *(float4*)&red[(h*2 + (cgu-2))*256 + jl*4] = v;
        }
    }
    __syncthreads();
    if (cgu < 2) {
        #pragma unroll
        for (int h = 0; h < 12; h++) {
            float4 o = *(const float4*)&red[(h*2 + cgu)*256 + jl*4];
            acc[h][0] += o.x; acc[h][1] += o.y; acc[h][2] += o.z; acc[h][3] += o.w;
        }
        if (cgu == 1) {
            #pragma unroll
            for (int h = 0; h < 12; h++) {
                float4 v; v.x=acc[h][0]; v.y=acc[h][1]; v.z=acc[h][2]; v.w=acc[h][3];
                *(float4*)&red[(h*2 + 1)*256 + jl*4] = v;
            }
        }
    }
    __syncthreads();
    if (cgu == 0) {
        #pragma unroll
        for (int h = 0; h < 12; h++) {
            float4 o = *(const float4*)&red[(h*2 + 1)*256 + jl*4];
            float s0 = sq_q[h*N + i];
            float4 sk = *(const float4*)&sq_k[h*N + j];
            float4 r;
            r.x = w_l*(acc[h][0] + o.x - ch[h]*(s0 + sk.x));
            r.y = w_l*(acc[h][1] + o.y - ch[h]*(s0 + sk.y));
            r.z = w_l*(acc[h][2] + o.z - ch[h]*(s0 + sk.z));
            r.w = w_l*(acc[h][3] + o.w - ch[h]*(s0 + sk.w));
            *(float4*)&a[((size_t)h*N + i)*N + j] = r;
        }
    }
}

// ---------------------------------------------------------------------------
// Kernel 3b: in-place softmax over last dim. one wave per (h,i) row.
// ---------------------------------------------------------------------------
__global__ __launch_bounds__(256) void k_softmax(float* __restrict__ a)
{
    int r = blockIdx.x*4 + (threadIdx.x >> 6);   // 6144 rows
    int l = threadIdx.x & 63;
    float* row = a + (size_t)r*N + l*8;
    float4 v0 = *(const float4*)row;
    float4 v1 = *(const float4*)(row + 4);
    float m = fmaxf(fmaxf(fmaxf(v0.x,v0.y),fmaxf(v0.z,v0.w)),
                    fmaxf(fmaxf(v1.x,v1.y),fmaxf(v1.z,v1.w)));
    for (int s = 32; s > 0; s >>= 1) m = fmaxf(m, __shfl_xor(m, s));
    v0.x = __expf(v0.x-m); v0.y = __expf(v0.y-m);
    v0.z = __expf(v0.z-m); v0.w = __expf(v0.w-m);
    v1.x = __expf(v1.x-m); v1.y = __expf(v1.y-m);
    v1.z = __expf(v1.z-m); v1.w = __expf(v1.w-m);
    float sm = v0.x+v0.y+v0.z+v0.w+v1.x+v1.y+v1.z+v1.w;
    for (int s = 32; s > 0; s >>= 1) sm += __shfl_xor(sm, s);
    float inv = 1.f/sm;
    v0.x*=inv; v0.y*=inv; v0.z*=inv; v0.w*=inv;
    v1.x*=inv; v1.y*=inv; v1.z*=inv; v1.w*=inv;
    *(float4*)row = v0;
    *(float4*)(row+4) = v1;
}

// ---------------------------------------------------------------------------
// Kernel 4: o1[(c,h),i] = sum_j a[h,i,j]*z[c,i,j]. grid (512 i, 2 c-halves).
// thread: cg = t&31 (2 c strided 32), hg = (t>>5)&1 (6 h), jq = t>>6 (j-quarter).
// ---------------------------------------------------------------------------
__global__ __launch_bounds__(256) void k_o1(
    const float* __restrict__ z, const float* __restrict__ a, float* __restrict__ cat)
{
    __shared__ float als[12*516];     // 24.8 KB
    __shared__ float zls[64*68];      // 17.4 KB
    int i = blockIdx.x;
    int c0 = blockIdx.y * 64;
    int t = threadIdx.x;
    int cg = t & 31, hg = (t>>5)&1, jq = t>>6;

    #pragma unroll
    for (int k = 0; k < 6; k++) {     // stage a 12x512 float4
        int idx = t + k*256;
        int h = idx >> 7, j4 = idx & 127;
        *(float4*)&als[h*516 + j4*4] = *(const float4*)&a[((size_t)h*N + i)*N + j4*4];
    }
    float acc[2][6] = {};
    for (int jc = 0; jc < 8; jc++) {
        __syncthreads();
        #pragma unroll
        for (int k = 0; k < 4; k++) { // stage z 64x64 float4
            int idx = t + k*256;
            int c = idx >> 4, j4 = idx & 15;
            *(float4*)&zls[c*68 + j4*4] =
                *(const float4*)&z[((size_t)(c0+c)*N + i)*N + jc*64 + j4*4];
        }
        __syncthreads();
        #pragma unroll
        for (int s = 0; s < 4; s++) {
            int jo = jq*16 + s*4;
            float4 z0 = *(const float4*)&zls[cg*68 + jo];
            float4 z1 = *(const float4*)&zls[(cg+32)*68 + jo];
            #pragma unroll
            for (int hh = 0; hh < 6; hh++) {
                float4 a4 = *(const float4*)&als[(hg*6+hh)*516 + jc*64 + jo];
                acc[0][hh] += z0.x*a4.x + z0.y*a4.y + z0.z*a4.z + z0.w*a4.w;
                acc[1][hh] += z1.x*a4.x + z1.y*a4.y + z1.z*a4.z + z1.w*a4.w;
            }
        }
    }
    __syncthreads();
    if (jq >= 2) {
        float* rb = &zls[((jq-2)*128 + (t & 127))*13];
        #pragma unroll
        for (int r = 0; r < 2; r++)
            #pragma unroll
            for (int hh = 0; hh < 6; hh++) rb[r*6+hh] = acc[r][hh];
    }
    __syncthreads();
    if (jq < 2) {
        const float* rb = &zls[(jq*128 + (t & 127))*13];
        #pragma unroll
        for (int r = 0; r < 2; r++)
            #pragma unroll
            for (int hh = 0; hh < 6; hh++) acc[r][hh] += rb[r*6+hh];
        if (jq == 1) {
            // FIX (R3 bug): write to slots 0..63 so jq==0 readers (t=0..63)
            // find their counterpart's partials. Was (t & 127) -> slots 64..127.
            float* rb2 = &als[(t & 63)*13];
            #pragma unroll
            for (int r = 0; r < 2; r++)
                #pragma unroll
                for (int hh = 0; hh < 6; hh++) rb2[r*6+hh] = acc[r][hh];
        }
    }
    __syncthreads();
    if (jq == 0) {
        const float* rb2 = &als[t*13];
        #pragma unroll
        for (int r = 0; r < 2; r++)
            #pragma unroll
            for (int hh = 0; hh < 6; hh++) {
                float v = acc[r][hh] + rb2[r*6+hh];
                int c = c0 + cg + 32*r;
                int h = hg*6 + hh;
                cat[(size_t)(c*H + h)*N + i] = v;
            }
    }
}

// ---------------------------------------------------------------------------
// Kernel 5: o2 + o3g. grid (12 h, 64 i-tiles of 8). 4-way j split.
// thread: il = t&7, rg = (t>>3)&7 (5 rows each), jq = t>>6.
// ---------------------------------------------------------------------------
__global__ __launch_bounds__(256) void k_o2o3g(
    const float* __restrict__ a, const float* __restrict__ proj, const float* __restrict__ vg,
    float* __restrict__ cat, float* __restrict__ o3g)
{
    __shared__ float ats[8*132];      // 4.2 KB
    __shared__ float vts[40*132];     // 21.1 KB
    int h = blockIdx.x, i0 = blockIdx.y*8;
    int t = threadIdx.x;
    int il = t & 7, rg = (t>>3)&7, jq = t>>6;
    const float* v = proj + 384*N;
    float acc[5] = {};
    for (int jc = 0; jc < 4; jc++) {
        __syncthreads();
        {   // a tile 8x128 float4: 1 per thread
            int ii = t >> 5, j4 = t & 31;
            *(float4*)&ats[ii*132 + j4*4] =
                *(const float4*)&a[((size_t)h*N + i0+ii)*N + jc*128 + j4*4];
        }
        #pragma unroll
        for (int k = 0; k < 5; k++) {  // v/vg tile 40x128 float4
            int idx = t + k*256;
            int r = idx >> 5, j4 = idx & 31;
            const float* src = (r < 16) ? (v + (size_t)(r*H + h)*N)
                : (vg + (size_t)(((r-16)>>3)*96 + h*PV + ((r-16)&7))*N);
            *(float4*)&vts[r*132 + j4*4] = *(const float4*)&src[jc*128 + j4*4];
        }
        __syncthreads();
        #pragma unroll
        for (int s = 0; s < 8; s++) {
            int jo = jq*32 + s*4;
            float4 a4 = *(const float4*)&ats[il*132 + jo];
            #pragma unroll
            for (int r = 0; r < 5; r++) {
                float4 v4 = *(const float4*)&vts[(rg*5+r)*132 + jo];
                acc[r] += v4.x*a4.x + v4.y*a4.y + v4.z*a4.z + v4.w*a4.w;
            }
        }
    }
    __syncthreads();
    if (jq >= 2) {
        float* rb = &ats[((jq-2)*64 + (t & 63))*5];
        #pragma unroll
        for (int r = 0; r < 5; r++) rb[r] = acc[r];
    }
    __syncthreads();
    if (jq < 2) {
        const float* rb = &ats[(jq*64 + (t & 63))*5];
        #pragma unroll
        for (int r = 0; r < 5; r++) acc[r] += rb[r];
        if (jq == 1) {
            float* rb2 = &ats[640 + (t & 63)*5];
            #pragma unroll
            for (int r = 0; r < 5; r++) rb2[r] = acc[r];
        }
    }
    __syncthreads();
    if (jq == 0) {
        const float* rb2 = &ats[640 + t*5];
        #pragma unroll
        for (int r = 0; r < 5; r++) {
            float val = acc[r] + rb2[r];
            int row = rg*5 + r;
            if (row < 16) cat[(size_t)(1536 + row*H + h)*N + i0 + il] = val;
            else { int rr = row - 16;
                   o3g[(size_t)((rr>>3)*96 + h*PV + (rr&7))*N + i0 + il] = val; }
        }
    }
}

// ---------------------------------------------------------------------------
// Kernel 6: inverse frame transform -> cat rows 1728..2015
// ---------------------------------------------------------------------------
__global__ void k_o3(const float* __restrict__ o3g,
                     const float* __restrict__ t_r, const float* __restrict__ t_t,
                     float* __restrict__ cat)
{
    int gid = blockIdx.x*blockDim.x + threadIdx.x;
    int i = gid & (N-1), hp = gid >> 9;
    if (hp >= 96) return;
    float x0 = o3g[(size_t)(0*96 + hp)*N + i] - t_t[i*3+0];
    float x1 = o3g[(size_t)(1*96 + hp)*N + i] - t_t[i*3+1];
    float x2 = o3g[(size_t)(2*96 + hp)*N + i] - t_t[i*3+2];
    #pragma unroll
    for (int d = 0; d < 3; d++) {
        float o = t_r[(i*3+0)*3+d]*x0 + t_r[(i*3+1)*3+d]*x1 + t_r[(i*3+2)*3+d]*x2;
        cat[(size_t)(1728 + d*96 + hp)*N + i] = o;
    }
}

// ---------------------------------------------------------------------------
// Kernel 6b: o3_norm -> cat row 2016
// ---------------------------------------------------------------------------
__global__ void k_norm(float* __restrict__ cat)
{
    int i = blockIdx.x*blockDim.x + threadIdx.x;
    if (i >= N) return;
    float acc = 0.f;
    for (int r = 0; r < 288; r++) {
        float v = cat[(size_t)(1728+r)*N + i];
        acc += v*v;
    }
    cat[(size_t)2016*N + i] = sqrtf(acc);
}

// ---------------------------------------------------------------------------
// Kernel 7: final GEMM, split-K=4 with atomics.
// ---------------------------------------------------------------------------
__global__ __launch_bounds__(256) void k_final(
    const float* __restrict__ Ws, const float* __restrict__ bs,
    const float* __restrict__ cat, float* __restrict__ out)
{
    __shared__ float Wt[16*33];
    __shared__ float Ct[32*66];
    int o0 = blockIdx.x*16, n0 = blockIdx.y*64;
    int ks = blockIdx.z;
    int kbeg = ks*505, kend = min(CATR, kbeg+505);
    int t = threadIdx.x;
    int og = t >> 6, nl = t & 63;
    float acc[4] = {};
    for (int c0 = kbeg; c0 < kend; c0 += 32) {
        __syncthreads();
        for (int k = 0; k < 2; k++) {
            int idx = t + k*256;
            int oo = idx >> 5, ccol = idx & 31;
            int c = c0 + ccol;
            Wt[oo*33 + ccol] = (c < kend) ? Ws[(size_t)(o0+oo)*CATR + c] : 0.f;
        }
        for (int k = 0; k < 4; k++) {
            int idx = t + k*256;
            int ccr = idx >> 5, j2 = idx & 31;
            int c = c0 + ccr;
            float2 vv; vv.x = 0.f; vv.y = 0.f;
            if (c < kend) vv = *(const float2*)&cat[(size_t)c*N + n0 + j2*2];
            *(float2*)&Ct[ccr*66 + j2*2] = vv;
        }
        __syncthreads();
        int klim = min(32, kend - c0);
        for (int kk = 0; kk < klim; kk++) {
            float cv = Ct[kk*66 + nl];
            #pragma unroll
            for (int r = 0; r < 4; r++)
                acc[r] += Wt[(og*4+r)*33 + kk] * cv;
        }
    }
    #pragma unroll
    for (int r = 0; r < 4; r++) {
        int o = o0 + og*4 + r;
        float val = acc[r];
        if (ks == 0) val += bs[o];
        atomicAdd(&out[(size_t)o*N + n0 + nl], val);
    }
}

// ---------------------------------------------------------------------------
extern "C" void kernel_launch(void* const* d_in, const int* in_sizes, int n_in,
                              void* d_out, int out_size, void* d_ws, size_t ws_size,
                              hipStream_t stream)
{
    const float* s     = (const float*)d_in[0];
    const float* z     = (const float*)d_in[1];
    const float* t_r   = (const float*)d_in[2];
    const float* t_t   = (const float*)d_in[3];
    const float* Wq    = (const float*)d_in[4];
    const float* Wk    = (const float*)d_in[5];
    const float* Wv    = (const float*)d_in[6];
    const float* Wqp   = (const float*)d_in[7];
    const float* Wkp   = (const float*)d_in[8];
    const float* Wvp   = (const float*)d_in[9];
    const float* Wb    = (const float*)d_in[10];
    const float* gamma = (const float*)d_in[11];
    const float* Ws    = (const float*)d_in[12];
    const float* bs    = (const float*)d_in[13];
    float* out = (float*)d_out;

    float* ws   = (float*)d_ws;
    float* proj = ws;                       // 1152*512
    float* qg   = proj + 1152*N;            // 144*512
    float* kg   = qg   + 144*N;             // 144*512
    float* vg   = kg   + 144*N;             // 288*512
    float* sq_q = vg   + 288*N;             // 12*512
    float* sq_k = sq_q + H*N;               // 12*512
    float* o3g  = sq_k + H*N;               // 288*512
    float* a    = o3g  + 288*N;             // 12*512*512 (logits, then softmaxed)
    float* cat  = a    + (size_t)H*N*N;     // 2017*512

    k_proj   <<<dim3(72,4),   256, 0, stream>>>(s, Wq, Wk, Wv, Wqp, Wkp, Wvp, proj);
    k_frames <<<384,          256, 0, stream>>>(proj, t_r, t_t, qg, kg, vg);
    k_sq     <<<48,           256, 0, stream>>>(qg, kg, sq_q, sq_k);
    k_logits <<<dim3(512,2),  256, 0, stream>>>(z, proj, qg, kg, sq_q, sq_k, Wb, gamma, a);
    k_softmax<<<1536,         256, 0, stream>>>(a);
    k_o1     <<<dim3(512,2),  256, 0, stream>>>(z, a, cat);
    k_o2o3g  <<<dim3(12,64),  256, 0, stream>>>(a, proj, vg, cat, o3g);
    k_o3     <<<192,          256, 0, stream>>>(o3g, t_r, t_t, cat);
    k_norm   <<<2,            256, 0, stream>>>(cat);
    hipMemsetAsync(out, 0, (size_t)CS*N*sizeof(float), stream);
    k_final  <<<dim3(24,8,4), 256, 0, stream>>>(Ws, bs, cat, out);
}

// Round 5
// 410.374 us; speedup vs baseline: 1.0191x; 1.0191x over previous
//
#include <hip/hip_runtime.h>
#include <math.h>

#define N 512
#define H 12
#define CC 16      // C
#define CZ 128
#define CS 384
#define PQ 4
#define PV 8
#define CATR 2017

// ---------------------------------------------------------------------------
// Kernel 1: all projections. out[o,n] = sum_c W_sel[o][c] * s[c,n], o in [0,1152)
// ---------------------------------------------------------------------------
__global__ __launch_bounds__(256) void k_proj(
    const float* __restrict__ s,
    const float* __restrict__ Wq, const float* __restrict__ Wk, const float* __restrict__ Wv,
    const float* __restrict__ Wqp, const float* __restrict__ Wkp, const float* __restrict__ Wvp,
    float* __restrict__ proj)
{
    __shared__ float Wt[16][33];
    __shared__ float St[32][128];
    int t = threadIdx.x;
    int o0 = blockIdx.x * 16;
    int n0 = blockIdx.y * 128;
    const float* Wsrc; int orow;
    if (o0 < 192)      { Wsrc = Wq;  orow = o0; }
    else if (o0 < 384) { Wsrc = Wk;  orow = o0-192; }
    else if (o0 < 576) { Wsrc = Wv;  orow = o0-384; }
    else if (o0 < 720) { Wsrc = Wqp; orow = o0-576; }
    else if (o0 < 864) { Wsrc = Wkp; orow = o0-720; }
    else               { Wsrc = Wvp; orow = o0-864; }

    int og = t >> 6, nl = t & 63;
    float acc[4][2] = {};
    for (int c0 = 0; c0 < CS; c0 += 32) {
        __syncthreads();
        for (int k = 0; k < 2; k++) {
            int idx = t + k*256;
            int oo = idx >> 5, ccol = idx & 31;
            Wt[oo][ccol] = Wsrc[(orow+oo)*CS + c0 + ccol];
        }
        for (int k = 0; k < 4; k++) {
            int idx = t + k*256;
            int ccr = idx >> 5, nn4 = idx & 31;
            float4 v = *(const float4*)&s[(c0+ccr)*N + n0 + nn4*4];
            *(float4*)&St[ccr][nn4*4] = v;
        }
        __syncthreads();
        for (int kk = 0; kk < 32; kk++) {
            float sv0 = St[kk][nl], sv1 = St[kk][nl+64];
            #pragma unroll
            for (int r = 0; r < 4; r++) {
                float w = Wt[og*4+r][kk];
                acc[r][0] += w * sv0;
                acc[r][1] += w * sv1;
            }
        }
    }
    for (int r = 0; r < 4; r++) {
        int o = o0 + og*4 + r;
        proj[o*N + n0 + nl]      = acc[r][0];
        proj[o*N + n0 + 64 + nl] = acc[r][1];
    }
}

// ---------------------------------------------------------------------------
// Kernel 2: apply frames.
// ---------------------------------------------------------------------------
__global__ void k_frames(const float* __restrict__ proj,
                         const float* __restrict__ t_r, const float* __restrict__ t_t,
                         float* __restrict__ qg, float* __restrict__ kg, float* __restrict__ vg)
{
    int gid = blockIdx.x * blockDim.x + threadIdx.x;
    int n = gid & (N-1);
    int hp = gid >> 9;
    if (hp >= 192) return;
    const float* src; float* dst; int rowb, stride;
    if (hp < 48)      { src = proj + 576*N; dst = qg; rowb = hp;    stride = 48; }
    else if (hp < 96) { src = proj + 720*N; dst = kg; rowb = hp-48; stride = 48; }
    else              { src = proj + 864*N; dst = vg; rowb = hp-96; stride = 96; }
    float x0 = src[(rowb + 0*stride)*N + n];
    float x1 = src[(rowb + 1*stride)*N + n];
    float x2 = src[(rowb + 2*stride)*N + n];
    #pragma unroll
    for (int d = 0; d < 3; d++) {
        float r0 = t_r[(n*3+d)*3+0], r1 = t_r[(n*3+d)*3+1], r2 = t_r[(n*3+d)*3+2];
        dst[(rowb + d*stride)*N + n] = r0*x0 + r1*x1 + r2*x2 + t_t[n*3+d];
    }
}

// ---------------------------------------------------------------------------
// Kernel 2b: squared norms per (h,n).
// ---------------------------------------------------------------------------
__global__ void k_sq(const float* __restrict__ qg, const float* __restrict__ kg,
                     float* __restrict__ sq_q, float* __restrict__ sq_k)
{
    int gid = blockIdx.x * blockDim.x + threadIdx.x;
    int n = gid & (N-1);
    int sel = gid >> 9;
    int h = sel % H;
    const float* g = (sel < H) ? qg : kg;
    float* outp = (sel < H) ? sq_q : sq_k;
    float acc = 0.f;
    #pragma unroll
    for (int d = 0; d < 3; d++)
        #pragma unroll
        for (int p = 0; p < PQ; p++) {
            float v = g[(size_t)((d*H + h)*PQ + p)*N + n];
            acc += v*v;
        }
    outp[h*N + n] = acc;
}

// ---------------------------------------------------------------------------
// Kernel 3: FUSED logits + softmax + o1. One block per i (512 blocks, 256 thr).
//  Pass A: stream z[:,i,:] -> logits in LDS (als). 4 waves own c-quarters.
//  Softmax in LDS, write a to global (for k_o2o3g).
//  Pass B: re-read z[:,i,:] (L2/L3-hot) tiled into LDS -> o1 -> cat.
//  HBM z traffic: once instead of twice.
// ---------------------------------------------------------------------------
__global__ __launch_bounds__(256) void k_attn_o1(
    const float* __restrict__ z, const float* __restrict__ proj,
    const float* __restrict__ qg, const float* __restrict__ kg,
    const float* __restrict__ sq_q, const float* __restrict__ sq_k,
    const float* __restrict__ Wb, const float* __restrict__ gamma,
    float* __restrict__ a, float* __restrict__ cat)
{
    __shared__ float als[12*516];     // 24.8 KB: logits -> softmaxed a
    __shared__ float zls[128*68];     // 34.8 KB: red buffer (pass A) / z tiles (pass B)
    int i = blockIdx.x;
    int t = threadIdx.x;
    int jl = t & 63;
    int cgu = __builtin_amdgcn_readfirstlane(t >> 6);   // wave id, uniform
    const size_t NN = (size_t)N*N;
    const float w_l  = 0.57735026918962584f;   // sqrt(1/3)
    const float w_c2 = 0.11785113019775793f;   // sqrt(1/18)/2

    float ch[12];
    #pragma unroll
    for (int h = 0; h < 12; h++) {
        float g = gamma[h];
        float sp = (g > 20.f) ? g : log1pf(expf(g));
        ch[h] = sp * w_c2;
    }

    // ================= Pass A: logits =================
    for (int jc = 0; jc < 2; jc++) {
        int j = jc*256 + jl*4;
        float acc[12][4] = {};

        // b_bias: 32 c per wave, 8 loads in flight
        {
            const float* zp = z + (size_t)(cgu*32)*NN + (size_t)i*N + j;
            for (int cc = 0; cc < 32; cc += 8) {
                float4 zb[8];
                #pragma unroll
                for (int u = 0; u < 8; u++)
                    zb[u] = *(const float4*)(zp + (size_t)(cc+u)*NN);
                #pragma unroll
                for (int u = 0; u < 8; u++) {
                    int c = cgu*32 + cc + u;
                    #pragma unroll
                    for (int h = 0; h < 12; h++) {
                        float w = Wb[h*CZ + c];           // uniform -> s_load
                        acc[h][0] += w*zb[u].x; acc[h][1] += w*zb[u].y;
                        acc[h][2] += w*zb[u].z; acc[h][3] += w*zb[u].w;
                    }
                }
            }
        }
        // qk/4: 4 c per wave
        {
            const float* q  = proj;
            const float* kk = proj + 192*N;
            #pragma unroll
            for (int cc = 0; cc < 4; cc++) {
                int c = cgu*4 + cc;
                #pragma unroll
                for (int h = 0; h < 12; h++) {
                    int r = c*12 + h;
                    float qv = 0.25f * q[(size_t)r*N + i];   // uniform
                    float4 k4 = *(const float4*)&kk[(size_t)r*N + j];
                    acc[h][0] += qv*k4.x; acc[h][1] += qv*k4.y;
                    acc[h][2] += qv*k4.z; acc[h][3] += qv*k4.w;
                }
            }
        }
        // +2*ch*(qg.kg): 3 dp per wave
        {
            #pragma unroll
            for (int dd = 0; dd < 3; dd++) {
                int dp = cgu*3 + dd; int d = dp >> 2, p = dp & 3;
                #pragma unroll
                for (int h = 0; h < 12; h++) {
                    int r = (d*12 + h)*4 + p;
                    float qv = 2.f * ch[h] * qg[(size_t)r*N + i];  // uniform
                    float4 k4 = *(const float4*)&kg[(size_t)r*N + j];
                    acc[h][0] += qv*k4.x; acc[h][1] += qv*k4.y;
                    acc[h][2] += qv*k4.z; acc[h][3] += qv*k4.w;
                }
            }
        }

        // tree reduce across 4 waves (red buffer inside zls)
        __syncthreads();   // previous iter's red reads done
        float* red = zls;
        if (cgu >= 2) {
            #pragma unroll
            for (int h = 0; h < 12; h++) {
                float4 v; v.x=acc[h][0]; v.y=acc[h][1]; v.z=acc[h][2]; v.w=acc[h][3];
                *(float4*)&red[(h*2 + (cgu-2))*256 + jl*4] = v;
            }
        }
        __syncthreads();
        if (cgu < 2) {
            #pragma unroll
            for (int h = 0; h < 12; h++) {
                float4 o = *(const float4*)&red[(h*2 + cgu)*256 + jl*4];
                acc[h][0] += o.x; acc[h][1] += o.y; acc[h][2] += o.z; acc[h][3] += o.w;
            }
            if (cgu == 1) {
                #pragma unroll
                for (int h = 0; h < 12; h++) {
                    float4 v; v.x=acc[h][0]; v.y=acc[h][1]; v.z=acc[h][2]; v.w=acc[h][3];
                    *(float4*)&red[(h*2 + 1)*256 + jl*4] = v;
                }
            }
        }
        __syncthreads();
        if (cgu == 0) {
            #pragma unroll
            for (int h = 0; h < 12; h++) {
                float4 o = *(const float4*)&red[(h*2 + 1)*256 + jl*4];
                float s0 = sq_q[h*N + i];
                float4 sk = *(const float4*)&sq_k[h*N + j];
                float4 r;
                r.x = w_l*(acc[h][0] + o.x - ch[h]*(s0 + sk.x));
                r.y = w_l*(acc[h][1] + o.y - ch[h]*(s0 + sk.y));
                r.z = w_l*(acc[h][2] + o.z - ch[h]*(s0 + sk.z));
                r.w = w_l*(acc[h][3] + o.w - ch[h]*(s0 + sk.w));
                *(float4*)&als[h*516 + jc*256 + jl*4] = r;
            }
        }
    }
    __syncthreads();

    // ================= Softmax (in LDS) =================
    // wave cgu handles rows h = cgu*3 .. cgu*3+2; 64 lanes x 8 elems
    #pragma unroll
    for (int hh = 0; hh < 3; hh++) {
        int h = cgu*3 + hh;
        float* row = &als[h*516 + jl*8];
        float4 v0 = *(const float4*)row;
        float4 v1 = *(const float4*)(row+4);
        float m = fmaxf(fmaxf(fmaxf(v0.x,v0.y),fmaxf(v0.z,v0.w)),
                        fmaxf(fmaxf(v1.x,v1.y),fmaxf(v1.z,v1.w)));
        for (int s = 32; s > 0; s >>= 1) m = fmaxf(m, __shfl_xor(m, s));
        v0.x = __expf(v0.x-m); v0.y = __expf(v0.y-m);
        v0.z = __expf(v0.z-m); v0.w = __expf(v0.w-m);
        v1.x = __expf(v1.x-m); v1.y = __expf(v1.y-m);
        v1.z = __expf(v1.z-m); v1.w = __expf(v1.w-m);
        float sm = v0.x+v0.y+v0.z+v0.w+v1.x+v1.y+v1.z+v1.w;
        for (int s = 32; s > 0; s >>= 1) sm += __shfl_xor(sm, s);
        float inv = 1.f/sm;
        v0.x*=inv; v0.y*=inv; v0.z*=inv; v0.w*=inv;
        v1.x*=inv; v1.y*=inv; v1.z*=inv; v1.w*=inv;
        *(float4*)row = v0;
        *(float4*)(row+4) = v1;
        // also persist a to global for k_o2o3g
        float* garow = &a[((size_t)h*N + i)*N + jl*8];
        *(float4*)garow = v0;
        *(float4*)(garow+4) = v1;
    }
    __syncthreads();

    // ================= Pass B: o1 =================
    // thread: cg = t&31 (4 c strided 32), hg = (t>>5)&1 (6 h), jq = t>>6.
    int cg = t & 31, hg = (t>>5)&1, jq = t>>6;
    float acc[4][6] = {};
    for (int jc = 0; jc < 8; jc++) {
        __syncthreads();
        #pragma unroll
        for (int k = 0; k < 8; k++) { // stage z 128x64 float4
            int idx = t + k*256;
            int c = idx >> 4, j4 = idx & 15;
            *(float4*)&zls[c*68 + j4*4] =
                *(const float4*)&z[((size_t)c*N + i)*N + jc*64 + j4*4];
        }
        __syncthreads();
        #pragma unroll
        for (int s = 0; s < 4; s++) {
            int jo = jq*16 + s*4;
            float4 a4[6];
            #pragma unroll
            for (int hh = 0; hh < 6; hh++)
                a4[hh] = *(const float4*)&als[(hg*6+hh)*516 + jc*64 + jo];
            #pragma unroll
            for (int r = 0; r < 4; r++) {
                float4 zz = *(const float4*)&zls[(cg + 32*r)*68 + jo];
                #pragma unroll
                for (int hh = 0; hh < 6; hh++)
                    acc[r][hh] += zz.x*a4[hh].x + zz.y*a4[hh].y
                                + zz.z*a4[hh].z + zz.w*a4[hh].w;
            }
        }
    }
    // cross-jq reduction: jq{2,3} -> zls slabs, jq{0,1} add, jq1 -> als, jq0 final
    __syncthreads();
    if (jq >= 2) {
        float* rb = &zls[((jq-2)*128 + (t & 127))*25];
        #pragma unroll
        for (int r = 0; r < 4; r++)
            #pragma unroll
            for (int hh = 0; hh < 6; hh++) rb[r*6+hh] = acc[r][hh];
    }
    __syncthreads();
    if (jq < 2) {
        const float* rb = &zls[(jq*128 + (t & 127))*25];
        #pragma unroll
        for (int r = 0; r < 4; r++)
            #pragma unroll
            for (int hh = 0; hh < 6; hh++) acc[r][hh] += rb[r*6+hh];
        if (jq == 1) {
            float* rb2 = &als[(t & 63)*25];
            #pragma unroll
            for (int r = 0; r < 4; r++)
                #pragma unroll
                for (int hh = 0; hh < 6; hh++) rb2[r*6+hh] = acc[r][hh];
        }
    }
    __syncthreads();
    if (jq == 0) {
        const float* rb2 = &als[t*25];
        #pragma unroll
        for (int r = 0; r < 4; r++)
            #pragma unroll
            for (int hh = 0; hh < 6; hh++) {
                float v = acc[r][hh] + rb2[r*6+hh];
                int c = cg + 32*r;
                int h = hg*6 + hh;
                cat[(size_t)(c*H + h)*N + i] = v;
            }
    }
}

// ---------------------------------------------------------------------------
// Kernel 5: o2 + o3g. grid (12 h, 64 i-tiles of 8). 4-way j split.
// ---------------------------------------------------------------------------
__global__ __launch_bounds__(256) void k_o2o3g(
    const float* __restrict__ a, const float* __restrict__ proj, const float* __restrict__ vg,
    float* __restrict__ cat, float* __restrict__ o3g)
{
    __shared__ float ats[8*132];      // 4.2 KB
    __shared__ float vts[40*132];     // 21.1 KB
    int h = blockIdx.x, i0 = blockIdx.y*8;
    int t = threadIdx.x;
    int il = t & 7, rg = (t>>3)&7, jq = t>>6;
    const float* v = proj + 384*N;
    float acc[5] = {};
    for (int jc = 0; jc < 4; jc++) {
        __syncthreads();
        {   // a tile 8x128 float4: 1 per thread
            int ii = t >> 5, j4 = t & 31;
            *(float4*)&ats[ii*132 + j4*4] =
                *(const float4*)&a[((size_t)h*N + i0+ii)*N + jc*128 + j4*4];
        }
        #pragma unroll
        for (int k = 0; k < 5; k++) {  // v/vg tile 40x128 float4
            int idx = t + k*256;
            int r = idx >> 5, j4 = idx & 31;
            const float* src = (r < 16) ? (v + (size_t)(r*H + h)*N)
                : (vg + (size_t)(((r-16)>>3)*96 + h*PV + ((r-16)&7))*N);
            *(float4*)&vts[r*132 + j4*4] = *(const float4*)&src[jc*128 + j4*4];
        }
        __syncthreads();
        #pragma unroll
        for (int s = 0; s < 8; s++) {
            int jo = jq*32 + s*4;
            float4 a4 = *(const float4*)&ats[il*132 + jo];
            #pragma unroll
            for (int r = 0; r < 5; r++) {
                float4 v4 = *(const float4*)&vts[(rg*5+r)*132 + jo];
                acc[r] += v4.x*a4.x + v4.y*a4.y + v4.z*a4.z + v4.w*a4.w;
            }
        }
    }
    __syncthreads();
    if (jq >= 2) {
        float* rb = &ats[((jq-2)*64 + (t & 63))*5];
        #pragma unroll
        for (int r = 0; r < 5; r++) rb[r] = acc[r];
    }
    __syncthreads();
    if (jq < 2) {
        const float* rb = &ats[(jq*64 + (t & 63))*5];
        #pragma unroll
        for (int r = 0; r < 5; r++) acc[r] += rb[r];
        if (jq == 1) {
            float* rb2 = &ats[640 + (t & 63)*5];
            #pragma unroll
            for (int r = 0; r < 5; r++) rb2[r] = acc[r];
        }
    }
    __syncthreads();
    if (jq == 0) {
        const float* rb2 = &ats[640 + t*5];
        #pragma unroll
        for (int r = 0; r < 5; r++) {
            float val = acc[r] + rb2[r];
            int row = rg*5 + r;
            if (row < 16) cat[(size_t)(1536 + row*H + h)*N + i0 + il] = val;
            else { int rr = row - 16;
                   o3g[(size_t)((rr>>3)*96 + h*PV + (rr&7))*N + i0 + il] = val; }
        }
    }
}

// ---------------------------------------------------------------------------
// Kernel 6: inverse frame transform -> cat rows 1728..2015
// ---------------------------------------------------------------------------
__global__ void k_o3(const float* __restrict__ o3g,
                     const float* __restrict__ t_r, const float* __restrict__ t_t,
                     float* __restrict__ cat)
{
    int gid = blockIdx.x*blockDim.x + threadIdx.x;
    int i = gid & (N-1), hp = gid >> 9;
    if (hp >= 96) return;
    float x0 = o3g[(size_t)(0*96 + hp)*N + i] - t_t[i*3+0];
    float x1 = o3g[(size_t)(1*96 + hp)*N + i] - t_t[i*3+1];
    float x2 = o3g[(size_t)(2*96 + hp)*N + i] - t_t[i*3+2];
    #pragma unroll
    for (int d = 0; d < 3; d++) {
        float o = t_r[(i*3+0)*3+d]*x0 + t_r[(i*3+1)*3+d]*x1 + t_r[(i*3+2)*3+d]*x2;
        cat[(size_t)(1728 + d*96 + hp)*N + i] = o;
    }
}

// ---------------------------------------------------------------------------
// Kernel 6b: o3_norm -> cat row 2016
// ---------------------------------------------------------------------------
__global__ void k_norm(float* __restrict__ cat)
{
    int i = blockIdx.x*blockDim.x + threadIdx.x;
    if (i >= N) return;
    float acc = 0.f;
    for (int r = 0; r < 288; r++) {
        float v = cat[(size_t)(1728+r)*N + i];
        acc += v*v;
    }
    cat[(size_t)2016*N + i] = sqrtf(acc);
}

// ---------------------------------------------------------------------------
// Kernel 7: final GEMM, split-K=4 with atomics.
// ---------------------------------------------------------------------------
__global__ __launch_bounds__(256) void k_final(
    const float* __restrict__ Ws, const float* __restrict__ bs,
    const float* __restrict__ cat, float* __restrict__ out)
{
    __shared__ float Wt[16*33];
    __shared__ float Ct[32*66];
    int o0 = blockIdx.x*16, n0 = blockIdx.y*64;
    int ks = blockIdx.z;
    int kbeg = ks*505, kend = min(CATR, kbeg+505);
    int t = threadIdx.x;
    int og = t >> 6, nl = t & 63;
    float acc[4] = {};
    for (int c0 = kbeg; c0 < kend; c0 += 32) {
        __syncthreads();
        for (int k = 0; k < 2; k++) {
            int idx = t + k*256;
            int oo = idx >> 5, ccol = idx & 31;
            int c = c0 + ccol;
            Wt[oo*33 + ccol] = (c < kend) ? Ws[(size_t)(o0+oo)*CATR + c] : 0.f;
        }
        for (int k = 0; k < 4; k++) {
            int idx = t + k*256;
            int ccr = idx >> 5, j2 = idx & 31;
            int c = c0 + ccr;
            float2 vv; vv.x = 0.f; vv.y = 0.f;
            if (c < kend) vv = *(const float2*)&cat[(size_t)c*N + n0 + j2*2];
            *(float2*)&Ct[ccr*66 + j2*2] = vv;
        }
        __syncthreads();
        int klim = min(32, kend - c0);
        for (int kk = 0; kk < klim; kk++) {
            float cv = Ct[kk*66 + nl];
            #pragma unroll
            for (int r = 0; r < 4; r++)
                acc[r] += Wt[(og*4+r)*33 + kk] * cv;
        }
    }
    #pragma unroll
    for (int r = 0; r < 4; r++) {
        int o = o0 + og*4 + r;
        float val = acc[r];
        if (ks == 0) val += bs[o];
        atomicAdd(&out[(size_t)o*N + n0 + nl], val);
    }
}

// ---------------------------------------------------------------------------
extern "C" void kernel_launch(void* const* d_in, const int* in_sizes, int n_in,
                              void* d_out, int out_size, void* d_ws, size_t ws_size,
                              hipStream_t stream)
{
    const float* s     = (const float*)d_in[0];
    const float* z     = (const float*)d_in[1];
    const float* t_r   = (const float*)d_in[2];
    const float* t_t   = (const float*)d_in[3];
    const float* Wq    = (const float*)d_in[4];
    const float* Wk    = (const float*)d_in[5];
    const float* Wv    = (const float*)d_in[6];
    const float* Wqp   = (const float*)d_in[7];
    const float* Wkp   = (const float*)d_in[8];
    const float* Wvp   = (const float*)d_in[9];
    const float* Wb    = (const float*)d_in[10];
    const float* gamma = (const float*)d_in[11];
    const float* Ws    = (const float*)d_in[12];
    const float* bs    = (const float*)d_in[13];
    float* out = (float*)d_out;

    float* ws   = (float*)d_ws;
    float* proj = ws;                       // 1152*512
    float* qg   = proj + 1152*N;            // 144*512
    float* kg   = qg   + 144*N;             // 144*512
    float* vg   = kg   + 144*N;             // 288*512
    float* sq_q = vg   + 288*N;             // 12*512
    float* sq_k = sq_q + H*N;               // 12*512
    float* o3g  = sq_k + H*N;               // 288*512
    float* a    = o3g  + 288*N;             // 12*512*512
    float* cat  = a    + (size_t)H*N*N;     // 2017*512

    k_proj   <<<dim3(72,4),   256, 0, stream>>>(s, Wq, Wk, Wv, Wqp, Wkp, Wvp, proj);
    k_frames <<<384,          256, 0, stream>>>(proj, t_r, t_t, qg, kg, vg);
    k_sq     <<<48,           256, 0, stream>>>(qg, kg, sq_q, sq_k);
    k_attn_o1<<<512,          256, 0, stream>>>(z, proj, qg, kg, sq_q, sq_k, Wb, gamma, a, cat);
    k_o2o3g  <<<dim3(12,64),  256, 0, stream>>>(a, proj, vg, cat, o3g);
    k_o3     <<<192,          256, 0, stream>>>(o3g, t_r, t_t, cat);
    k_norm   <<<2,            256, 0, stream>>>(cat);
    hipMemsetAsync(out, 0, (size_t)CS*N*sizeof(float), stream);
    k_final  <<<dim3(24,8,4), 256, 0, stream>>>(Ws, bs, cat, out);
}